// Round 8
// baseline (216.216 us; speedup 1.0000x reference)
//
#include <hip/hip_runtime.h>

// B=4, C=C2=1024, E=1024, D=1024, NH(head dim)=16, G=64 groups. Rows B*C=4096.

typedef _Float16 f16x8 __attribute__((ext_vector_type(8)));
typedef _Float16 f16x4 __attribute__((ext_vector_type(4)));
typedef _Float16 f16x2 __attribute__((ext_vector_type(2)));
typedef float    f32x4 __attribute__((ext_vector_type(4)));
typedef float    f32x16 __attribute__((ext_vector_type(16)));

// global -> LDS direct DMA, 16 B per lane. LDS dest = wave-uniform base + lane*16.
#define GLOAD_LDS16(gp, lp)                                              \
    __builtin_amdgcn_global_load_lds(                                    \
        (const __attribute__((address_space(1))) void*)(gp),             \
        (__attribute__((address_space(3))) void*)(lp), 16, 0, 0)

static __device__ __forceinline__ f16x8 pack8f(const float* p) {
    f16x2 a = __builtin_bit_cast(f16x2, __builtin_amdgcn_cvt_pkrtz(p[0], p[1]));
    f16x2 b = __builtin_bit_cast(f16x2, __builtin_amdgcn_cvt_pkrtz(p[2], p[3]));
    f16x2 c = __builtin_bit_cast(f16x2, __builtin_amdgcn_cvt_pkrtz(p[4], p[5]));
    f16x2 d = __builtin_bit_cast(f16x2, __builtin_amdgcn_cvt_pkrtz(p[6], p[7]));
    f16x8 r;
    r[0] = a[0]; r[1] = a[1]; r[2] = b[0]; r[3] = b[1];
    r[4] = c[0]; r[5] = c[1]; r[6] = d[0]; r[7] = d[1];
    return r;
}

// ---- prep: fp32->fp16 convert of x1,x2 (blocks 0..8191) + transpose-convert of the
// ---- 4 weights into (N,K) f16 (blocks 8192..12287), one launch ----
__global__ __launch_bounds__(256) void prep_kernel(
        const float* __restrict__ x1, const float* __restrict__ x2,
        const float* __restrict__ W0, const float* __restrict__ W1,
        const float* __restrict__ W2, const float* __restrict__ W3,
        _Float16* __restrict__ y1, _Float16* __restrict__ y2,
        _Float16* __restrict__ T0, _Float16* __restrict__ T1,
        _Float16* __restrict__ T2, _Float16* __restrict__ T3) {
    int bx = blockIdx.x, tid = threadIdx.x;
    if (bx < 8192) {
        int i = bx * 256 + tid;              // 2M float4 total
        const float* x = (i < 1048576) ? x1 : x2;
        _Float16* y = (i < 1048576) ? y1 : y2;
        int j = i & 1048575;
        float4 v = ((const float4*)x)[j];
        f16x4 h = { (_Float16)v.x, (_Float16)v.y, (_Float16)v.z, (_Float16)v.w };
        ((f16x4*)y)[j] = h;
    } else {
        int z = (bx - 8192) >> 10;
        const float* W = (z == 0) ? W0 : (z == 1) ? W1 : (z == 2) ? W2 : W3;
        _Float16* WT = (z == 0) ? T0 : (z == 1) ? T1 : (z == 2) ? T2 : T3;
        int t = (bx - 8192) & 1023;
        int c0 = (t & 31) * 32, r0 = (t >> 5) * 32;
        __shared__ float tile[32][33];
        int tx = tid & 31, ty = tid >> 5;    // 32 x 8
#pragma unroll
        for (int i = 0; i < 32; i += 8)
            tile[ty + i][tx] = W[(r0 + ty + i) * 1024 + (c0 + tx)];
        __syncthreads();
#pragma unroll
        for (int i = 0; i < 32; i += 8)
            WT[(c0 + ty + i) * 1024 + (r0 + tx)] = (_Float16)tile[tx][ty + i];
    }
}

// ------------- m97-style MTx128 GEMM body (pre-offset pointers, K=1024) -------------
// block 256 (4 waves, 2x2 over MT x 128), BK=64, global_load_lds w16, 16x16x32 MFMA.
// R17 (verified: gemm_qkv 9.4M conflict-cycles -> off top-5, total -7us): T2-style
// LDS XOR-swizzle, both-sides (rule #21). DMA dest linear; global SOURCE column
// pre-swizzled (slot s of row r holds linear column s^(r&7)); reads XOR the same
// involution (row&7 == col&7 at read). Per-lane slot = (ki*4+quad)^(col&7):
// 2-way alias (free). Permutation stays inside each 128B line.
template <int MT, bool OUTF32>
static __device__ __forceinline__ void gemm_body(const _Float16* __restrict__ Atile,
                                                 const _Float16* __restrict__ BTtile,
                                                 void* __restrict__ Ctile,
                                                 _Float16* As, _Float16* Bs) {
    constexpr int AF = MT / 32;              // A staging rounds & m-frags per wave
    const int tid = threadIdx.x, lane = tid & 63, wave = tid >> 6;
    const int wm = wave >> 1, wn = wave & 1;
    const int col = lane & 15, quad = lane >> 4;

    f32x4 acc[AF][4];
#pragma unroll
    for (int i = 0; i < AF; i++)
#pragma unroll
        for (int j = 0; j < 4; j++) acc[i][j] = (f32x4){0.f, 0.f, 0.f, 0.f};

    const int srow = wave * 8 + (lane >> 3);
    // swizzled source column: slot (lane&7) of row (..|lane>>3) holds col slot^(r&7)
    const int sch = ((lane & 7) ^ (lane >> 3)) * 8;
    const _Float16* Ag = Atile + (size_t)srow * 1024 + sch;
    const _Float16* Bg = BTtile + (size_t)srow * 1024 + sch;
    _Float16* Asl = As + wave * 512;
    _Float16* Bsl = Bs + wave * 512;

    const int rsw = (col & 7) * 8;           // read-side XOR (row&7 == col&7)

    for (int kt = 0; kt < 16; kt++) {
        __syncthreads();
#pragma unroll
        for (int c = 0; c < AF; c++)
            GLOAD_LDS16(Ag + (size_t)(c * 32) * 1024 + kt * 64, Asl + c * 2048);
#pragma unroll
        for (int c = 0; c < 4; c++)
            GLOAD_LDS16(Bg + (size_t)(c * 32) * 1024 + kt * 64, Bsl + c * 2048);
        __syncthreads();
#pragma unroll
        for (int ki = 0; ki < 2; ki++) {
            f16x8 af[AF], bf[4];
#pragma unroll
            for (int i = 0; i < AF; i++)
                af[i] = *(const f16x8*)(As + (((wm * (MT / 2) + i * 16 + col) * 64
                                               + ki * 32 + quad * 8) ^ rsw));
#pragma unroll
            for (int j = 0; j < 4; j++)
                bf[j] = *(const f16x8*)(Bs + (((wn * 64 + j * 16 + col) * 64
                                               + ki * 32 + quad * 8) ^ rsw));
#pragma unroll
            for (int i = 0; i < AF; i++)
#pragma unroll
                for (int j = 0; j < 4; j++)
                    acc[i][j] = __builtin_amdgcn_mfma_f32_16x16x32_f16(af[i], bf[j], acc[i][j], 0, 0, 0);
        }
    }

#pragma unroll
    for (int i = 0; i < AF; i++)
#pragma unroll
        for (int ii = 0; ii < 4; ii++) {
            int row = wm * (MT / 2) + i * 16 + quad * 4 + ii;
#pragma unroll
            for (int j = 0; j < 4; j++) {
                int cc = wn * 64 + j * 16 + col;
                if (OUTF32) ((float*)Ctile)[(size_t)row * 1024 + cc] = acc[i][j][ii];
                else ((_Float16*)Ctile)[(size_t)row * 1024 + cc] = (_Float16)acc[i][j][ii];
            }
        }
}

// Fused Q + (KV as N=2048) projections, flat 768-block grid (128x128 tiles):
__global__ __launch_bounds__(256, 3) void gemm_qkv_kernel(
        const _Float16* __restrict__ x1h, const _Float16* __restrict__ x2h,
        const _Float16* __restrict__ WqT, const _Float16* __restrict__ WkvT,
        _Float16* __restrict__ Qh, _Float16* __restrict__ Kh, _Float16* __restrict__ Vh) {
    __shared__ _Float16 As[128 * 64], Bs[128 * 64];
    int gx = blockIdx.x;
    const _Float16 *A, *BT;
    _Float16* C;
    int m0, n0;
    if (gx < 256) {
        m0 = (gx >> 3) * 128; n0 = (gx & 7) * 128;
        A = x1h; BT = WqT + (size_t)n0 * 1024; C = Qh + n0;
    } else {
        int idx = gx - 256;
        m0 = (idx >> 4) * 128;
        int nb = idx & 15;
        n0 = nb * 128;                        // 0..2047 within stacked KV
        A = x2h; BT = WkvT + (size_t)n0 * 1024;
        C = (nb < 8) ? (Kh + n0) : (Vh + (n0 - 1024));
    }
    gemm_body<128, false>(A + (size_t)m0 * 1024, BT, (void*)(C + (size_t)m0 * 1024), As, Bs);
}

// Wo GEMM: 64x128 tiles -> 512 blocks (2 blocks/CU co-residency).
__global__ __launch_bounds__(256, 4) void gemm_wo_kernel(const _Float16* __restrict__ Ah,
                                                         const _Float16* __restrict__ WoT,
                                                         float* __restrict__ out) {
    __shared__ _Float16 As[64 * 64], Bs[128 * 64];
    int gx = blockIdx.x;
    int m0 = (gx >> 3) * 64, n0 = (gx & 7) * 128;
    gemm_body<64, true>(Ah + (size_t)m0 * 1024, WoT + (size_t)n0 * 1024,
                        (void*)(out + (size_t)m0 * 1024 + n0), As, Bs);
}

// ------------- MFMA flash attention (fixed-max softmax), per (b,g) pair -------------
// R18 = R16 + K-in-registers (LDS bypass). Evidence (R7): VALU+trans issue floor
// ~21us of 41.6us wall; per-CU LDS pipe ~17us, 1/3 of it the K ds_read_b128s that
// ALL 8 waves redundantly re-read (8x amplification of the CU-shared LDS pipe);
// wall ~ sum not max of the pipes (lockstep dependent chains).
// Fix: each wave loads its own K fragment from GLOBAL (per-lane addr = the old DMA
// source formula with wave->t), one uniform pointer += 32 rows/t-iter, linear over
// all 32 t-iters (no chunk cases). Depth-1 rolling prefetch (akn loaded under the
// current iter's exp work) hides L2 ~200cy; K is L2-hot (8x re-read, ~7 TB/s << L2
// peak). Final prefetch reads into the adjacent ws buffer (mapped, unused).
// K-DMA + K ds_reads + K LDS gone; barrier now fences only V staging. LDS 8.2 KB.
// VGPR ~50, (512,8) pins <=64 -> 8 waves/SIMD. Tripwire: WRITE_SIZE >9MB = spill.
// V path unchanged (R16): waves 4-7 stage via swizzled ds_write_b32 (2 lanes/bank),
// write-late, double-buffered; XCD-coherent block swizzle (FETCH 74->39 verified).
__global__ __launch_bounds__(512, 8) void attn_kernel(const _Float16* __restrict__ Qh,
                                                      const _Float16* __restrict__ Kh,
                                                      const _Float16* __restrict__ Vh,
                                                      _Float16* __restrict__ Ah) {
    // ---- XCD-coherent swizzle ----
    int L = blockIdx.x;                      // 0..1023
    int xcd = L & 7, y = L >> 3;             // HW: XCD ~= L%8 (round-robin)
    int halfpid = xcd + ((y & 15) << 3);     // 0..127, fixed per XCD
    int pid = (halfpid << 1) | ((y >> 4) & 1);
    int qch = y >> 5;                        // 0..3
    int b = pid >> 6, g = pid & 63;

    __shared__ _Float16 VA[4096];    // 2 bufs x [pvblk:8][kb3][head^swz|hi][klow]
    __shared__ _Float16 ones[8];     // broadcast all-1.0 A-frag for L rows

    const _Float16* Kg = Kh + (size_t)(b * 1024) * 1024 + g * 16;
    const _Float16* Vg = Vh + (size_t)(b * 1024) * 1024 + g * 16;
    int tid = threadIdx.x;
    if (tid < 8) ones[tid] = (_Float16)1.f;

    int lane = tid & 63, wave = tid >> 6;    // wave 0..7
    int n = lane & 31, h5 = lane >> 5;       // n = q (S/PV col), also PV A-row m
    int q0 = qch * 256 + wave * 32;

    // Q B-frag: B[k=head=h5*8+j][n=q]; fold 0.25*log2(e) -> scores in log2 domain.
    f16x8 qf;
    {
        f16x8 t = *(const f16x8*)(Qh + (size_t)(b * 1024 + q0 + n) * 1024 + g * 16 + h5 * 8);
#pragma unroll
        for (int j = 0; j < 8; j++) qf[j] = (_Float16)((float)t[j] * 0.360673760f);
    }

    f32x16 acc = {0.f, 0.f, 0.f, 0.f, 0.f, 0.f, 0.f, 0.f,
                  0.f, 0.f, 0.f, 0.f, 0.f, 0.f, 0.f, 0.f};
    const f32x16 zero16 = acc;

    // ---- per-wave K fragment pointer (global, permuted rows; all 8 waves equal) ----
    const int pl = lane & 31;
    const int kperm = (pl & 19) | ((pl & 4) << 1) | ((pl & 8) >> 1);   // swap bits 2,3
    const _Float16* kp = Kg + (size_t)kperm * 1024 + (lane >> 5) * 8;
    f16x8 akc = *(const f16x8*)kp;           // t-iter 0 fragment
    kp += 32 * 1024;

    // ---- V staging (waves 4-7): u in [0,256), pair (vk0,vk0+1), 4 heads ----
    const int u = tid & 255;
    const int vk0 = (u & 63) * 2;
    const int hq = u >> 6;                   // head quad 0..3
    const int vpart = hq >> 1, jb = (hq & 1) * 4;
    const _Float16* vsrcA = Vg + (size_t)vk0 * 1024 + vpart * 8 + jb;
    const int vbw3 = ((((vk0 >> 4) * 256) + ((vk0 >> 3) & 1) * 128 + vpart * 64 + (vk0 & 7))
                      ^ (((vk0 >> 3) & 7) << 3)) ^ (jb * 8);

    // ---- compute-side V read: single base reg + folded per-pvblk immediates ----
    // addr(s) = ((vb0 ^ ((s&3)<<4)) | ((s&3)<<8) | ((s>>2)<<10)) & vmask
    const int vb0 = h5 * 128 + ((n & 8) | ((n & 7) ^ h5)) * 8;
    const int vmask = (n < 16) ? -1 : 0;     // ones-lanes: offset 0 -> broadcast
    const _Float16* vrb = (n < 16) ? VA : ones;
    const int vbufstep = (n < 16) ? 2048 : 0;

    // ---- prologue: stage V chunk 0 into buf 0 ----
    if (tid >= 256) {
        f16x4 va = *(const f16x4*)(vsrcA);
        f16x4 vb = *(const f16x4*)(vsrcA + 1024);
#pragma unroll
        for (int jj = 0; jj < 4; jj++) {
            f16x2 pr; pr[0] = va[jj]; pr[1] = vb[jj];
            *(f16x2*)(VA + (vbw3 ^ (jj * 8))) = pr;
        }
    }

    for (int c = 0; c < 8; c++) {            // 128-key chunks
        __syncthreads();                     // V buf[c&1] staged; buf[c&1^1] free
        const int cb = c & 1;
        f16x4 va, vb;
        if (c < 7 && tid >= 256) {           // issue next chunk's V loads early
            va = *(const f16x4*)(vsrcA + (size_t)((c + 1) * 128) * 1024);
            vb = *(const f16x4*)(vsrcA + (size_t)((c + 1) * 128) * 1024 + 1024);
        }
        const _Float16* vrbc = vrb + cb * vbufstep;

        __builtin_amdgcn_s_setprio(1);
#pragma unroll
        for (int t = 0; t < 4; t++) {        // 32 keys per iteration
            // rolling K prefetch: load t+1's fragment under this iter's exp work.
            // (final iteration reads 2KB past K into Vh -- mapped ws, unused)
            f16x8 akn = *(const f16x8*)kp;
            kp += 32 * 1024;
            f32x16 s = __builtin_amdgcn_mfma_f32_32x32x16_f16(akc, qf, zero16, 0, 0, 0);
            float p[16];
#pragma unroll
            for (int i = 0; i < 16; i++) p[i] = __builtin_amdgcn_exp2f(s[i]);
            f16x8 pb0 = pack8f(p);           // keys t*32 + 0..15  (k=h5*8+j)
            f16x8 pb1 = pack8f(p + 8);       // keys t*32 + 16..31
            const int o0 = ((vb0 ^ (((2 * t) & 3) << 4)) | (((2 * t) & 3) << 8)
                            | (((2 * t) >> 2) << 10)) & vmask;
            const int o1 = ((vb0 ^ (((2 * t + 1) & 3) << 4)) | (((2 * t + 1) & 3) << 8)
                            | (((2 * t + 1) >> 2) << 10)) & vmask;
            f16x8 av0 = *(const f16x8*)(vrbc + o0);
            f16x8 av1 = *(const f16x8*)(vrbc + o1);
            acc = __builtin_amdgcn_mfma_f32_32x32x16_f16(av0, pb0, acc, 0, 0, 0);
            acc = __builtin_amdgcn_mfma_f32_32x32x16_f16(av1, pb1, acc, 0, 0, 0);
            akc = akn;
        }
        __builtin_amdgcn_s_setprio(0);

        if (c < 7 && tid >= 256) {           // write-late: V regs -> buf^1
#pragma unroll
            for (int jj = 0; jj < 4; jj++) {
                f16x2 pr; pr[0] = va[jj]; pr[1] = vb[jj];
                *(f16x2*)(VA + (cb ^ 1) * 2048 + (vbw3 ^ (jj * 8))) = pr;
            }
        }
    }

    // acc C-layout: col q=n; regs 0-7 -> heads, regs 8-15 -> L (all equal = key-sum).
    float rl = 1.0f / acc[8];
    f16x4 o0, o1;
#pragma unroll
    for (int i = 0; i < 4; i++) o0[i] = (_Float16)(acc[i] * rl);       // heads 4*h5+0..3
#pragma unroll
    for (int i = 0; i < 4; i++) o1[i] = (_Float16)(acc[4 + i] * rl);   // heads 4*h5+8..11
    _Float16* ob = Ah + (size_t)(b * 1024 + q0 + n) * 1024 + g * 16 + h5 * 4;
    *(f16x4*)(ob) = o0;
    *(f16x4*)(ob + 8) = o1;
}

extern "C" void kernel_launch(void* const* d_in, const int* in_sizes, int n_in,
                              void* d_out, int out_size, void* d_ws, size_t ws_size,
                              hipStream_t stream) {
    const float* x1 = (const float*)d_in[0];
    const float* x2 = (const float*)d_in[1];
    const float* Wq = (const float*)d_in[2];
    const float* Wk = (const float*)d_in[3];
    const float* Wv = (const float*)d_in[4];
    const float* Wo = (const float*)d_in[5];

    char* ws = (char*)d_ws;
    const size_t MB = 1u << 20;
    if (ws_size < 56 * MB) return;

    _Float16* x1h = (_Float16*)(ws + 0 * MB);   // 4096x1024
    _Float16* x2h = (_Float16*)(ws + 8 * MB);   // 4096x1024
    _Float16* WqT = (_Float16*)(ws + 16 * MB);  // 1024x1024 (N,K)
    _Float16* WkT = (_Float16*)(ws + 18 * MB);  // contiguous with WvT -> stacked (2048,1024)
    _Float16* WvT = (_Float16*)(ws + 20 * MB);
    _Float16* WoT = (_Float16*)(ws + 22 * MB);
    _Float16* Qh  = (_Float16*)(ws + 24 * MB);  // 4096x1024
    _Float16* Kh  = (_Float16*)(ws + 32 * MB);
    _Float16* Vh  = (_Float16*)(ws + 40 * MB);
    _Float16* Ah  = (_Float16*)(ws + 48 * MB);

    prep_kernel<<<12288, 256, 0, stream>>>(x1, x2, Wq, Wk, Wv, Wo,
                                           x1h, x2h, WqT, WkT, WvT, WoT);

    gemm_qkv_kernel<<<768, 256, 0, stream>>>(x1h, x2h, WqT, WkT, Qh, Kh, Vh);

    attn_kernel<<<1024, 512, 0, stream>>>(Qh, Kh, Vh, Ah);

    gemm_wo_kernel<<<512, 256, 0, stream>>>(Ah, WoT, (float*)d_out);
}

// Round 9
// 202.519 us; speedup vs baseline: 1.0676x; 1.0676x over previous
//
#include <hip/hip_runtime.h>

// B=4, C=C2=1024, E=1024, D=1024, NH(head dim)=16, G=64 groups. Rows B*C=4096.

typedef _Float16 f16x8 __attribute__((ext_vector_type(8)));
typedef _Float16 f16x4 __attribute__((ext_vector_type(4)));
typedef _Float16 f16x2 __attribute__((ext_vector_type(2)));
typedef float    f32x4 __attribute__((ext_vector_type(4)));
typedef float    f32x16 __attribute__((ext_vector_type(16)));

// global -> LDS direct DMA, 16 B per lane. LDS dest = wave-uniform base + lane*16.
#define GLOAD_LDS16(gp, lp)                                              \
    __builtin_amdgcn_global_load_lds(                                    \
        (const __attribute__((address_space(1))) void*)(gp),             \
        (__attribute__((address_space(3))) void*)(lp), 16, 0, 0)

static __device__ __forceinline__ f16x8 pack8f(const float* p) {
    f16x2 a = __builtin_bit_cast(f16x2, __builtin_amdgcn_cvt_pkrtz(p[0], p[1]));
    f16x2 b = __builtin_bit_cast(f16x2, __builtin_amdgcn_cvt_pkrtz(p[2], p[3]));
    f16x2 c = __builtin_bit_cast(f16x2, __builtin_amdgcn_cvt_pkrtz(p[4], p[5]));
    f16x2 d = __builtin_bit_cast(f16x2, __builtin_amdgcn_cvt_pkrtz(p[6], p[7]));
    f16x8 r;
    r[0] = a[0]; r[1] = a[1]; r[2] = b[0]; r[3] = b[1];
    r[4] = c[0]; r[5] = c[1]; r[6] = d[0]; r[7] = d[1];
    return r;
}

// ---- prep: fp32->fp16 convert of x1,x2 (blocks 0..8191) + transpose-convert of the
// ---- 4 weights into (N,K) f16 (blocks 8192..12287), one launch ----
__global__ __launch_bounds__(256) void prep_kernel(
        const float* __restrict__ x1, const float* __restrict__ x2,
        const float* __restrict__ W0, const float* __restrict__ W1,
        const float* __restrict__ W2, const float* __restrict__ W3,
        _Float16* __restrict__ y1, _Float16* __restrict__ y2,
        _Float16* __restrict__ T0, _Float16* __restrict__ T1,
        _Float16* __restrict__ T2, _Float16* __restrict__ T3) {
    int bx = blockIdx.x, tid = threadIdx.x;
    if (bx < 8192) {
        int i = bx * 256 + tid;              // 2M float4 total
        const float* x = (i < 1048576) ? x1 : x2;
        _Float16* y = (i < 1048576) ? y1 : y2;
        int j = i & 1048575;
        float4 v = ((const float4*)x)[j];
        f16x4 h = { (_Float16)v.x, (_Float16)v.y, (_Float16)v.z, (_Float16)v.w };
        ((f16x4*)y)[j] = h;
    } else {
        int z = (bx - 8192) >> 10;
        const float* W = (z == 0) ? W0 : (z == 1) ? W1 : (z == 2) ? W2 : W3;
        _Float16* WT = (z == 0) ? T0 : (z == 1) ? T1 : (z == 2) ? T2 : T3;
        int t = (bx - 8192) & 1023;
        int c0 = (t & 31) * 32, r0 = (t >> 5) * 32;
        __shared__ float tile[32][33];
        int tx = tid & 31, ty = tid >> 5;    // 32 x 8
#pragma unroll
        for (int i = 0; i < 32; i += 8)
            tile[ty + i][tx] = W[(r0 + ty + i) * 1024 + (c0 + tx)];
        __syncthreads();
#pragma unroll
        for (int i = 0; i < 32; i += 8)
            WT[(c0 + ty + i) * 1024 + (r0 + tx)] = (_Float16)tile[tx][ty + i];
    }
}

// ------------- m97-style MTx128 GEMM body (pre-offset pointers, K=1024) -------------
// block 256 (4 waves, 2x2 over MT x 128), BK=64, global_load_lds w16, 16x16x32 MFMA.
// R17 (verified: gemm_qkv 9.4M conflict-cycles -> off top-5, total -7us): T2-style
// LDS XOR-swizzle, both-sides (rule #21). DMA dest linear; global SOURCE column
// pre-swizzled (slot s of row r holds linear column s^(r&7)); reads XOR the same
// involution (row&7 == col&7 at read). Per-lane slot = (ki*4+quad)^(col&7):
// 2-way alias (free). Permutation stays inside each 128B line.
template <int MT, bool OUTF32>
static __device__ __forceinline__ void gemm_body(const _Float16* __restrict__ Atile,
                                                 const _Float16* __restrict__ BTtile,
                                                 void* __restrict__ Ctile,
                                                 _Float16* As, _Float16* Bs) {
    constexpr int AF = MT / 32;              // A staging rounds & m-frags per wave
    const int tid = threadIdx.x, lane = tid & 63, wave = tid >> 6;
    const int wm = wave >> 1, wn = wave & 1;
    const int col = lane & 15, quad = lane >> 4;

    f32x4 acc[AF][4];
#pragma unroll
    for (int i = 0; i < AF; i++)
#pragma unroll
        for (int j = 0; j < 4; j++) acc[i][j] = (f32x4){0.f, 0.f, 0.f, 0.f};

    const int srow = wave * 8 + (lane >> 3);
    // swizzled source column: slot (lane&7) of row (..|lane>>3) holds col slot^(r&7)
    const int sch = ((lane & 7) ^ (lane >> 3)) * 8;
    const _Float16* Ag = Atile + (size_t)srow * 1024 + sch;
    const _Float16* Bg = BTtile + (size_t)srow * 1024 + sch;
    _Float16* Asl = As + wave * 512;
    _Float16* Bsl = Bs + wave * 512;

    const int rsw = (col & 7) * 8;           // read-side XOR (row&7 == col&7)

    for (int kt = 0; kt < 16; kt++) {
        __syncthreads();
#pragma unroll
        for (int c = 0; c < AF; c++)
            GLOAD_LDS16(Ag + (size_t)(c * 32) * 1024 + kt * 64, Asl + c * 2048);
#pragma unroll
        for (int c = 0; c < 4; c++)
            GLOAD_LDS16(Bg + (size_t)(c * 32) * 1024 + kt * 64, Bsl + c * 2048);
        __syncthreads();
#pragma unroll
        for (int ki = 0; ki < 2; ki++) {
            f16x8 af[AF], bf[4];
#pragma unroll
            for (int i = 0; i < AF; i++)
                af[i] = *(const f16x8*)(As + (((wm * (MT / 2) + i * 16 + col) * 64
                                               + ki * 32 + quad * 8) ^ rsw));
#pragma unroll
            for (int j = 0; j < 4; j++)
                bf[j] = *(const f16x8*)(Bs + (((wn * 64 + j * 16 + col) * 64
                                               + ki * 32 + quad * 8) ^ rsw));
#pragma unroll
            for (int i = 0; i < AF; i++)
#pragma unroll
                for (int j = 0; j < 4; j++)
                    acc[i][j] = __builtin_amdgcn_mfma_f32_16x16x32_f16(af[i], bf[j], acc[i][j], 0, 0, 0);
        }
    }

#pragma unroll
    for (int i = 0; i < AF; i++)
#pragma unroll
        for (int ii = 0; ii < 4; ii++) {
            int row = wm * (MT / 2) + i * 16 + quad * 4 + ii;
#pragma unroll
            for (int j = 0; j < 4; j++) {
                int cc = wn * 64 + j * 16 + col;
                if (OUTF32) ((float*)Ctile)[(size_t)row * 1024 + cc] = acc[i][j][ii];
                else ((_Float16*)Ctile)[(size_t)row * 1024 + cc] = (_Float16)acc[i][j][ii];
            }
        }
}

// Fused Q + (KV as N=2048) projections, flat 768-block grid (128x128 tiles):
__global__ __launch_bounds__(256, 3) void gemm_qkv_kernel(
        const _Float16* __restrict__ x1h, const _Float16* __restrict__ x2h,
        const _Float16* __restrict__ WqT, const _Float16* __restrict__ WkvT,
        _Float16* __restrict__ Qh, _Float16* __restrict__ Kh, _Float16* __restrict__ Vh) {
    __shared__ _Float16 As[128 * 64], Bs[128 * 64];
    int gx = blockIdx.x;
    const _Float16 *A, *BT;
    _Float16* C;
    int m0, n0;
    if (gx < 256) {
        m0 = (gx >> 3) * 128; n0 = (gx & 7) * 128;
        A = x1h; BT = WqT + (size_t)n0 * 1024; C = Qh + n0;
    } else {
        int idx = gx - 256;
        m0 = (idx >> 4) * 128;
        int nb = idx & 15;
        n0 = nb * 128;                        // 0..2047 within stacked KV
        A = x2h; BT = WkvT + (size_t)n0 * 1024;
        C = (nb < 8) ? (Kh + n0) : (Vh + (n0 - 1024));
    }
    gemm_body<128, false>(A + (size_t)m0 * 1024, BT, (void*)(C + (size_t)m0 * 1024), As, Bs);
}

// Wo GEMM: 64x128 tiles -> 512 blocks (2 blocks/CU co-residency).
__global__ __launch_bounds__(256, 4) void gemm_wo_kernel(const _Float16* __restrict__ Ah,
                                                         const _Float16* __restrict__ WoT,
                                                         float* __restrict__ out) {
    __shared__ _Float16 As[64 * 64], Bs[128 * 64];
    int gx = blockIdx.x;
    int m0 = (gx >> 3) * 64, n0 = (gx & 7) * 128;
    gemm_body<64, true>(Ah + (size_t)m0 * 1024, WoT + (size_t)n0 * 1024,
                        (void*)(out + (size_t)m0 * 1024 + n0), As, Bs);
}

// ------------- MFMA flash attention (fixed-max softmax), per (b,g) pair -------------
// R19 = R18 with the ONE spill fix: __launch_bounds__(512,6).
// R18 post-mortem: gfx950's UNIFIED VGPR/AGPR file means launch_bounds(512,8) = 64
// TOTAL regs/wave, which must cover ~48 arch VGPRs + 16 AGPRs (acc) -> compiler
// clamped arch to 32 and spilled 14 dwords/thread (WRITE_SIZE 37MB, attn 76us).
// (512,6) = 80 total; demand ~50 arch + 16 AGPR = 66 <= 80. R15 verified this
// budget spill-free (40+16=56<=80). K-in-reg logic itself is harness-verified
// correct (R18 passed, same absmax).
// Design (R18): each wave loads its own K fragment from GLOBAL (per-lane permuted
// addr; uniform pointer += 32 rows/t-iter, linear over all 32 t-iters); depth-1
// rolling prefetch under the exp work; K L2-hot (8x block-level re-read). K-DMA,
// K ds_reads, K LDS all gone; barrier fences only V staging. LDS 8.2 KB.
// Final prefetch reads 2KB past K into Vh (mapped ws, unused).
// V path (R16): waves 4-7 stage via swizzled ds_write_b32 (2 lanes/bank),
// write-late, double-buffered; XCD-coherent block swizzle (FETCH 74->39 verified).
// Tripwire: WRITE_SIZE > 9MB = spill -> abandon K-in-reg, revert to R16 attn.
__global__ __launch_bounds__(512, 6) void attn_kernel(const _Float16* __restrict__ Qh,
                                                      const _Float16* __restrict__ Kh,
                                                      const _Float16* __restrict__ Vh,
                                                      _Float16* __restrict__ Ah) {
    // ---- XCD-coherent swizzle ----
    int L = blockIdx.x;                      // 0..1023
    int xcd = L & 7, y = L >> 3;             // HW: XCD ~= L%8 (round-robin)
    int halfpid = xcd + ((y & 15) << 3);     // 0..127, fixed per XCD
    int pid = (halfpid << 1) | ((y >> 4) & 1);
    int qch = y >> 5;                        // 0..3
    int b = pid >> 6, g = pid & 63;

    __shared__ _Float16 VA[4096];    // 2 bufs x [pvblk:8][kb3][head^swz|hi][klow]
    __shared__ _Float16 ones[8];     // broadcast all-1.0 A-frag for L rows

    const _Float16* Kg = Kh + (size_t)(b * 1024) * 1024 + g * 16;
    const _Float16* Vg = Vh + (size_t)(b * 1024) * 1024 + g * 16;
    int tid = threadIdx.x;
    if (tid < 8) ones[tid] = (_Float16)1.f;

    int lane = tid & 63, wave = tid >> 6;    // wave 0..7
    int n = lane & 31, h5 = lane >> 5;       // n = q (S/PV col), also PV A-row m
    int q0 = qch * 256 + wave * 32;

    // Q B-frag: B[k=head=h5*8+j][n=q]; fold 0.25*log2(e) -> scores in log2 domain.
    f16x8 qf;
    {
        f16x8 t = *(const f16x8*)(Qh + (size_t)(b * 1024 + q0 + n) * 1024 + g * 16 + h5 * 8);
#pragma unroll
        for (int j = 0; j < 8; j++) qf[j] = (_Float16)((float)t[j] * 0.360673760f);
    }

    f32x16 acc = {0.f, 0.f, 0.f, 0.f, 0.f, 0.f, 0.f, 0.f,
                  0.f, 0.f, 0.f, 0.f, 0.f, 0.f, 0.f, 0.f};
    const f32x16 zero16 = acc;

    // ---- per-wave K fragment pointer (global, permuted rows; all 8 waves equal) ----
    const int pl = lane & 31;
    const int kperm = (pl & 19) | ((pl & 4) << 1) | ((pl & 8) >> 1);   // swap bits 2,3
    const _Float16* kp = Kg + (size_t)kperm * 1024 + (lane >> 5) * 8;
    f16x8 akc = *(const f16x8*)kp;           // t-iter 0 fragment
    kp += 32 * 1024;

    // ---- V staging (waves 4-7): u in [0,256), pair (vk0,vk0+1), 4 heads ----
    const int u = tid & 255;
    const int vk0 = (u & 63) * 2;
    const int hq = u >> 6;                   // head quad 0..3
    const int vpart = hq >> 1, jb = (hq & 1) * 4;
    const _Float16* vsrcA = Vg + (size_t)vk0 * 1024 + vpart * 8 + jb;
    const int vbw3 = ((((vk0 >> 4) * 256) + ((vk0 >> 3) & 1) * 128 + vpart * 64 + (vk0 & 7))
                      ^ (((vk0 >> 3) & 7) << 3)) ^ (jb * 8);

    // ---- compute-side V read: single base reg + folded per-pvblk immediates ----
    // addr(s) = ((vb0 ^ ((s&3)<<4)) | ((s&3)<<8) | ((s>>2)<<10)) & vmask
    const int vb0 = h5 * 128 + ((n & 8) | ((n & 7) ^ h5)) * 8;
    const int vmask = (n < 16) ? -1 : 0;     // ones-lanes: offset 0 -> broadcast
    const _Float16* vrb = (n < 16) ? VA : ones;
    const int vbufstep = (n < 16) ? 2048 : 0;

    // ---- prologue: stage V chunk 0 into buf 0 ----
    if (tid >= 256) {
        f16x4 va = *(const f16x4*)(vsrcA);
        f16x4 vb = *(const f16x4*)(vsrcA + 1024);
#pragma unroll
        for (int jj = 0; jj < 4; jj++) {
            f16x2 pr; pr[0] = va[jj]; pr[1] = vb[jj];
            *(f16x2*)(VA + (vbw3 ^ (jj * 8))) = pr;
        }
    }

    for (int c = 0; c < 8; c++) {            // 128-key chunks
        __syncthreads();                     // V buf[c&1] staged; buf[c&1^1] free
        const int cb = c & 1;
        f16x4 va, vb;
        if (c < 7 && tid >= 256) {           // issue next chunk's V loads early
            va = *(const f16x4*)(vsrcA + (size_t)((c + 1) * 128) * 1024);
            vb = *(const f16x4*)(vsrcA + (size_t)((c + 1) * 128) * 1024 + 1024);
        }
        const _Float16* vrbc = vrb + cb * vbufstep;

        __builtin_amdgcn_s_setprio(1);
#pragma unroll
        for (int t = 0; t < 4; t++) {        // 32 keys per iteration
            // rolling K prefetch: load t+1's fragment under this iter's exp work.
            // (final iteration reads 2KB past K into Vh -- mapped ws, unused)
            f16x8 akn = *(const f16x8*)kp;
            kp += 32 * 1024;
            f32x16 s = __builtin_amdgcn_mfma_f32_32x32x16_f16(akc, qf, zero16, 0, 0, 0);
            float p[16];
#pragma unroll
            for (int i = 0; i < 16; i++) p[i] = __builtin_amdgcn_exp2f(s[i]);
            f16x8 pb0 = pack8f(p);           // keys t*32 + 0..15  (k=h5*8+j)
            f16x8 pb1 = pack8f(p + 8);       // keys t*32 + 16..31
            const int o0 = ((vb0 ^ (((2 * t) & 3) << 4)) | (((2 * t) & 3) << 8)
                            | (((2 * t) >> 2) << 10)) & vmask;
            const int o1 = ((vb0 ^ (((2 * t + 1) & 3) << 4)) | (((2 * t + 1) & 3) << 8)
                            | (((2 * t + 1) >> 2) << 10)) & vmask;
            f16x8 av0 = *(const f16x8*)(vrbc + o0);
            f16x8 av1 = *(const f16x8*)(vrbc + o1);
            acc = __builtin_amdgcn_mfma_f32_32x32x16_f16(av0, pb0, acc, 0, 0, 0);
            acc = __builtin_amdgcn_mfma_f32_32x32x16_f16(av1, pb1, acc, 0, 0, 0);
            akc = akn;
        }
        __builtin_amdgcn_s_setprio(0);

        if (c < 7 && tid >= 256) {           // write-late: V regs -> buf^1
#pragma unroll
            for (int jj = 0; jj < 4; jj++) {
                f16x2 pr; pr[0] = va[jj]; pr[1] = vb[jj];
                *(f16x2*)(VA + (cb ^ 1) * 2048 + (vbw3 ^ (jj * 8))) = pr;
            }
        }
    }

    // acc C-layout: col q=n; regs 0-7 -> heads, regs 8-15 -> L (all equal = key-sum).
    float rl = 1.0f / acc[8];
    f16x4 o0, o1;
#pragma unroll
    for (int i = 0; i < 4; i++) o0[i] = (_Float16)(acc[i] * rl);       // heads 4*h5+0..3
#pragma unroll
    for (int i = 0; i < 4; i++) o1[i] = (_Float16)(acc[4 + i] * rl);   // heads 4*h5+8..11
    _Float16* ob = Ah + (size_t)(b * 1024 + q0 + n) * 1024 + g * 16 + h5 * 4;
    *(f16x4*)(ob) = o0;
    *(f16x4*)(ob + 8) = o1;
}

extern "C" void kernel_launch(void* const* d_in, const int* in_sizes, int n_in,
                              void* d_out, int out_size, void* d_ws, size_t ws_size,
                              hipStream_t stream) {
    const float* x1 = (const float*)d_in[0];
    const float* x2 = (const float*)d_in[1];
    const float* Wq = (const float*)d_in[2];
    const float* Wk = (const float*)d_in[3];
    const float* Wv = (const float*)d_in[4];
    const float* Wo = (const float*)d_in[5];

    char* ws = (char*)d_ws;
    const size_t MB = 1u << 20;
    if (ws_size < 56 * MB) return;

    _Float16* x1h = (_Float16*)(ws + 0 * MB);   // 4096x1024
    _Float16* x2h = (_Float16*)(ws + 8 * MB);   // 4096x1024
    _Float16* WqT = (_Float16*)(ws + 16 * MB);  // 1024x1024 (N,K)
    _Float16* WkT = (_Float16*)(ws + 18 * MB);  // contiguous with WvT -> stacked (2048,1024)
    _Float16* WvT = (_Float16*)(ws + 20 * MB);
    _Float16* WoT = (_Float16*)(ws + 22 * MB);
    _Float16* Qh  = (_Float16*)(ws + 24 * MB);  // 4096x1024
    _Float16* Kh  = (_Float16*)(ws + 32 * MB);
    _Float16* Vh  = (_Float16*)(ws + 40 * MB);
    _Float16* Ah  = (_Float16*)(ws + 48 * MB);

    prep_kernel<<<12288, 256, 0, stream>>>(x1, x2, Wq, Wk, Wv, Wo,
                                           x1h, x2h, WqT, WkT, WvT, WoT);

    gemm_qkv_kernel<<<768, 256, 0, stream>>>(x1h, x2h, WqT, WkT, Qh, Kh, Vh);

    attn_kernel<<<1024, 512, 0, stream>>>(Qh, Kh, Vh, Ah);

    gemm_wo_kernel<<<512, 256, 0, stream>>>(Ah, WoT, (float*)d_out);
}

// Round 10
// 187.516 us; speedup vs baseline: 1.1531x; 1.0800x over previous
//
#include <hip/hip_runtime.h>

// B=4, C=C2=1024, E=1024, D=1024, NH(head dim)=16, G=64 groups. Rows B*C=4096.

typedef _Float16 f16x8 __attribute__((ext_vector_type(8)));
typedef _Float16 f16x4 __attribute__((ext_vector_type(4)));
typedef _Float16 f16x2 __attribute__((ext_vector_type(2)));
typedef float    f32x4 __attribute__((ext_vector_type(4)));
typedef float    f32x16 __attribute__((ext_vector_type(16)));

// global -> LDS direct DMA, 16 B per lane. LDS dest = wave-uniform base + lane*16.
#define GLOAD_LDS16(gp, lp)                                              \
    __builtin_amdgcn_global_load_lds(                                    \
        (const __attribute__((address_space(1))) void*)(gp),             \
        (__attribute__((address_space(3))) void*)(lp), 16, 0, 0)

static __device__ __forceinline__ f16x8 pack8f(const float* p) {
    f16x2 a = __builtin_bit_cast(f16x2, __builtin_amdgcn_cvt_pkrtz(p[0], p[1]));
    f16x2 b = __builtin_bit_cast(f16x2, __builtin_amdgcn_cvt_pkrtz(p[2], p[3]));
    f16x2 c = __builtin_bit_cast(f16x2, __builtin_amdgcn_cvt_pkrtz(p[4], p[5]));
    f16x2 d = __builtin_bit_cast(f16x2, __builtin_amdgcn_cvt_pkrtz(p[6], p[7]));
    f16x8 r;
    r[0] = a[0]; r[1] = a[1]; r[2] = b[0]; r[3] = b[1];
    r[4] = c[0]; r[5] = c[1]; r[6] = d[0]; r[7] = d[1];
    return r;
}

// ---- prep: fp32->fp16 convert of x1,x2 (blocks 0..8191) + transpose-convert of the
// ---- 4 weights into (N,K) f16 (blocks 8192..12287), one launch ----
__global__ __launch_bounds__(256) void prep_kernel(
        const float* __restrict__ x1, const float* __restrict__ x2,
        const float* __restrict__ W0, const float* __restrict__ W1,
        const float* __restrict__ W2, const float* __restrict__ W3,
        _Float16* __restrict__ y1, _Float16* __restrict__ y2,
        _Float16* __restrict__ T0, _Float16* __restrict__ T1,
        _Float16* __restrict__ T2, _Float16* __restrict__ T3) {
    int bx = blockIdx.x, tid = threadIdx.x;
    if (bx < 8192) {
        int i = bx * 256 + tid;              // 2M float4 total
        const float* x = (i < 1048576) ? x1 : x2;
        _Float16* y = (i < 1048576) ? y1 : y2;
        int j = i & 1048575;
        float4 v = ((const float4*)x)[j];
        f16x4 h = { (_Float16)v.x, (_Float16)v.y, (_Float16)v.z, (_Float16)v.w };
        ((f16x4*)y)[j] = h;
    } else {
        int z = (bx - 8192) >> 10;
        const float* W = (z == 0) ? W0 : (z == 1) ? W1 : (z == 2) ? W2 : W3;
        _Float16* WT = (z == 0) ? T0 : (z == 1) ? T1 : (z == 2) ? T2 : T3;
        int t = (bx - 8192) & 1023;
        int c0 = (t & 31) * 32, r0 = (t >> 5) * 32;
        __shared__ float tile[32][33];
        int tx = tid & 31, ty = tid >> 5;    // 32 x 8
#pragma unroll
        for (int i = 0; i < 32; i += 8)
            tile[ty + i][tx] = W[(r0 + ty + i) * 1024 + (c0 + tx)];
        __syncthreads();
#pragma unroll
        for (int i = 0; i < 32; i += 8)
            WT[(c0 + ty + i) * 1024 + (r0 + tx)] = (_Float16)tile[tx][ty + i];
    }
}

// ------------- m97-style MTx128 GEMM body (pre-offset pointers, K=1024) -------------
// block 256 (4 waves, 2x2 over MT x 128), BK=64, global_load_lds w16, 16x16x32 MFMA.
// R17 (verified: gemm_qkv 9.4M conflict-cycles -> off top-5, total -7us): T2-style
// LDS XOR-swizzle, both-sides (rule #21). DMA dest linear; global SOURCE column
// pre-swizzled (slot s of row r holds linear column s^(r&7)); reads XOR the same
// involution (row&7 == col&7 at read). Per-lane slot = (ki*4+quad)^(col&7):
// 2-way alias (free). Permutation stays inside each 128B line.
template <int MT, bool OUTF32>
static __device__ __forceinline__ void gemm_body(const _Float16* __restrict__ Atile,
                                                 const _Float16* __restrict__ BTtile,
                                                 void* __restrict__ Ctile,
                                                 _Float16* As, _Float16* Bs) {
    constexpr int AF = MT / 32;              // A staging rounds & m-frags per wave
    const int tid = threadIdx.x, lane = tid & 63, wave = tid >> 6;
    const int wm = wave >> 1, wn = wave & 1;
    const int col = lane & 15, quad = lane >> 4;

    f32x4 acc[AF][4];
#pragma unroll
    for (int i = 0; i < AF; i++)
#pragma unroll
        for (int j = 0; j < 4; j++) acc[i][j] = (f32x4){0.f, 0.f, 0.f, 0.f};

    const int srow = wave * 8 + (lane >> 3);
    // swizzled source column: slot (lane&7) of row (..|lane>>3) holds col slot^(r&7)
    const int sch = ((lane & 7) ^ (lane >> 3)) * 8;
    const _Float16* Ag = Atile + (size_t)srow * 1024 + sch;
    const _Float16* Bg = BTtile + (size_t)srow * 1024 + sch;
    _Float16* Asl = As + wave * 512;
    _Float16* Bsl = Bs + wave * 512;

    const int rsw = (col & 7) * 8;           // read-side XOR (row&7 == col&7)

    for (int kt = 0; kt < 16; kt++) {
        __syncthreads();
#pragma unroll
        for (int c = 0; c < AF; c++)
            GLOAD_LDS16(Ag + (size_t)(c * 32) * 1024 + kt * 64, Asl + c * 2048);
#pragma unroll
        for (int c = 0; c < 4; c++)
            GLOAD_LDS16(Bg + (size_t)(c * 32) * 1024 + kt * 64, Bsl + c * 2048);
        __syncthreads();
#pragma unroll
        for (int ki = 0; ki < 2; ki++) {
            f16x8 af[AF], bf[4];
#pragma unroll
            for (int i = 0; i < AF; i++)
                af[i] = *(const f16x8*)(As + (((wm * (MT / 2) + i * 16 + col) * 64
                                               + ki * 32 + quad * 8) ^ rsw));
#pragma unroll
            for (int j = 0; j < 4; j++)
                bf[j] = *(const f16x8*)(Bs + (((wn * 64 + j * 16 + col) * 64
                                               + ki * 32 + quad * 8) ^ rsw));
#pragma unroll
            for (int i = 0; i < AF; i++)
#pragma unroll
                for (int j = 0; j < 4; j++)
                    acc[i][j] = __builtin_amdgcn_mfma_f32_16x16x32_f16(af[i], bf[j], acc[i][j], 0, 0, 0);
        }
    }

#pragma unroll
    for (int i = 0; i < AF; i++)
#pragma unroll
        for (int ii = 0; ii < 4; ii++) {
            int row = wm * (MT / 2) + i * 16 + quad * 4 + ii;
#pragma unroll
            for (int j = 0; j < 4; j++) {
                int cc = wn * 64 + j * 16 + col;
                if (OUTF32) ((float*)Ctile)[(size_t)row * 1024 + cc] = acc[i][j][ii];
                else ((_Float16*)Ctile)[(size_t)row * 1024 + cc] = (_Float16)acc[i][j][ii];
            }
        }
}

// Fused Q + (KV as N=2048) projections, flat 768-block grid (128x128 tiles):
__global__ __launch_bounds__(256, 3) void gemm_qkv_kernel(
        const _Float16* __restrict__ x1h, const _Float16* __restrict__ x2h,
        const _Float16* __restrict__ WqT, const _Float16* __restrict__ WkvT,
        _Float16* __restrict__ Qh, _Float16* __restrict__ Kh, _Float16* __restrict__ Vh) {
    __shared__ _Float16 As[128 * 64], Bs[128 * 64];
    int gx = blockIdx.x;
    const _Float16 *A, *BT;
    _Float16* C;
    int m0, n0;
    if (gx < 256) {
        m0 = (gx >> 3) * 128; n0 = (gx & 7) * 128;
        A = x1h; BT = WqT + (size_t)n0 * 1024; C = Qh + n0;
    } else {
        int idx = gx - 256;
        m0 = (idx >> 4) * 128;
        int nb = idx & 15;
        n0 = nb * 128;                        // 0..2047 within stacked KV
        A = x2h; BT = WkvT + (size_t)n0 * 1024;
        C = (nb < 8) ? (Kh + n0) : (Vh + (n0 - 1024));
    }
    gemm_body<128, false>(A + (size_t)m0 * 1024, BT, (void*)(C + (size_t)m0 * 1024), As, Bs);
}

// Wo GEMM: 64x128 tiles -> 512 blocks (2 blocks/CU co-residency).
__global__ __launch_bounds__(256, 4) void gemm_wo_kernel(const _Float16* __restrict__ Ah,
                                                         const _Float16* __restrict__ WoT,
                                                         float* __restrict__ out) {
    __shared__ _Float16 As[64 * 64], Bs[128 * 64];
    int gx = blockIdx.x;
    int m0 = (gx >> 3) * 64, n0 = (gx & 7) * 128;
    gemm_body<64, true>(Ah + (size_t)m0 * 1024, WoT + (size_t)n0 * 1024,
                        (void*)(out + (size_t)m0 * 1024 + n0), As, Bs);
}

// ------------- MFMA flash attention (fixed-max softmax), per (b,g) pair -------------
// R20 = exact revert to the R16 attn (session-best measured state: attn 41.6us,
// total 179.2us). K-in-registers abandoned per tripwire after two spill failures:
// the kernel's irreducible live state is ~72 regs (40 arch + 16 acc + 16 zero16 in
// the unified gfx950 VGPR/AGPR file); +8 arch regs of K state exceeds the 80-reg
// (512,6) budget -> 4-14 dword/thread scratch spill (R18: 37MB, R19: 16.5MB).
// Structure: XCD-coherent block swizzle (FETCH 74->39 MB verified), double-buffered
// LDS, ONE barrier per chunk, K staged via global_load_lds DMA (pre-permuted global
// addrs, linear LDS dest), V staged by waves 4-7 (swizzled ds_write_b32, 2
// lanes/bank), write-late, setprio around compute.
__global__ __launch_bounds__(512, 6) void attn_kernel(const _Float16* __restrict__ Qh,
                                                      const _Float16* __restrict__ Kh,
                                                      const _Float16* __restrict__ Vh,
                                                      _Float16* __restrict__ Ah) {
    // ---- XCD-coherent swizzle ----
    int L = blockIdx.x;                      // 0..1023
    int xcd = L & 7, y = L >> 3;             // HW: XCD ~= L%8 (round-robin)
    int halfpid = xcd + ((y & 15) << 3);     // 0..127, fixed per XCD
    int pid = (halfpid << 1) | ((y >> 4) & 1);
    int qch = y >> 5;                        // 0..3
    int b = pid >> 6, g = pid & 63;

    __shared__ _Float16 KA[4096];    // 2 bufs x [t:4][lane:64][8 halves]
    __shared__ _Float16 VA[4096];    // 2 bufs x [pvblk:8][kb3][head^swz|hi][klow]
    __shared__ _Float16 ones[8];     // broadcast all-1.0 A-frag for L rows

    const _Float16* Kg = Kh + (size_t)(b * 1024) * 1024 + g * 16;
    const _Float16* Vg = Vh + (size_t)(b * 1024) * 1024 + g * 16;
    int tid = threadIdx.x;
    if (tid < 8) ones[tid] = (_Float16)1.f;

    int lane = tid & 63, wave = tid >> 6;    // wave 0..7
    int n = lane & 31, h5 = lane >> 5;       // n = q (S/PV col), also PV A-row m
    int q0 = qch * 256 + wave * 32;

    // Q B-frag: B[k=head=h5*8+j][n=q]; fold 0.25*log2(e) -> scores in log2 domain.
    f16x8 qf;
    {
        f16x8 t = *(const f16x8*)(Qh + (size_t)(b * 1024 + q0 + n) * 1024 + g * 16 + h5 * 8);
#pragma unroll
        for (int j = 0; j < 8; j++) qf[j] = (_Float16)((float)t[j] * 0.360673760f);
    }

    f32x16 acc = {0.f, 0.f, 0.f, 0.f, 0.f, 0.f, 0.f, 0.f,
                  0.f, 0.f, 0.f, 0.f, 0.f, 0.f, 0.f, 0.f};
    const f32x16 zero16 = acc;

    // ---- K DMA source (waves 0-3): per-lane pre-permuted global addr ----
    const int pl = lane & 31;
    const int kperm = (pl & 19) | ((pl & 4) << 1) | ((pl & 8) >> 1);   // swap bits 2,3
    const _Float16* ksrc = Kg + (size_t)((wave & 3) * 32 + kperm) * 1024 + (lane >> 5) * 8;
    _Float16* kdst = KA + (wave & 3) * 512;          // + bufsel*2048

    // ---- V staging (waves 4-7): u in [0,256), pair (vk0,vk0+1), 4 heads ----
    const int u = tid & 255;
    const int vk0 = (u & 63) * 2;
    const int hq = u >> 6;                   // head quad 0..3
    const int vpart = hq >> 1, jb = (hq & 1) * 4;
    const _Float16* vsrcA = Vg + (size_t)vk0 * 1024 + vpart * 8 + jb;
    const int vbw3 = ((((vk0 >> 4) * 256) + ((vk0 >> 3) & 1) * 128 + vpart * 64 + (vk0 & 7))
                      ^ (((vk0 >> 3) & 7) << 3)) ^ (jb * 8);

    // ---- compute-side V read: single base reg + folded per-pvblk immediates ----
    // addr(s) = ((vb0 ^ ((s&3)<<4)) | ((s&3)<<8) | ((s>>2)<<10)) & vmask
    const int vb0 = h5 * 128 + ((n & 8) | ((n & 7) ^ h5)) * 8;
    const int vmask = (n < 16) ? -1 : 0;     // ones-lanes: offset 0 -> broadcast
    const _Float16* vrb = (n < 16) ? VA : ones;
    const int vbufstep = (n < 16) ? 2048 : 0;

    // ---- prologue: stage chunk 0 into buf 0 ----
    if (tid < 256) {
        GLOAD_LDS16(ksrc, kdst);
    } else {
        f16x4 va = *(const f16x4*)(vsrcA);
        f16x4 vb = *(const f16x4*)(vsrcA + 1024);
#pragma unroll
        for (int jj = 0; jj < 4; jj++) {
            f16x2 pr; pr[0] = va[jj]; pr[1] = vb[jj];
            *(f16x2*)(VA + (vbw3 ^ (jj * 8))) = pr;
        }
    }

    for (int c = 0; c < 8; c++) {            // 128-key chunks
        __syncthreads();                     // buf[c&1] staged; buf[c&1^1] free
        const int cb = c & 1;
        f16x4 va, vb;
        if (c < 7) {                         // issue next chunk's staging early
            if (tid < 256) {
                GLOAD_LDS16(ksrc + (size_t)((c + 1) * 128) * 1024, kdst + (cb ^ 1) * 2048);
            } else {
                va = *(const f16x4*)(vsrcA + (size_t)((c + 1) * 128) * 1024);
                vb = *(const f16x4*)(vsrcA + (size_t)((c + 1) * 128) * 1024 + 1024);
            }
        }
        const _Float16* akc = KA + cb * 2048;
        const _Float16* vrbc = vrb + cb * vbufstep;

        __builtin_amdgcn_s_setprio(1);
#pragma unroll
        for (int t = 0; t < 4; t++) {        // 32 keys per iteration
            f16x8 ak = *(const f16x8*)(akc + (t * 64 + lane) * 8);
            f32x16 s = __builtin_amdgcn_mfma_f32_32x32x16_f16(ak, qf, zero16, 0, 0, 0);
            float p[16];
#pragma unroll
            for (int i = 0; i < 16; i++) p[i] = __builtin_amdgcn_exp2f(s[i]);
            f16x8 pb0 = pack8f(p);           // keys t*32 + 0..15  (k=h5*8+j)
            f16x8 pb1 = pack8f(p + 8);       // keys t*32 + 16..31
            const int o0 = ((vb0 ^ (((2 * t) & 3) << 4)) | (((2 * t) & 3) << 8)
                            | (((2 * t) >> 2) << 10)) & vmask;
            const int o1 = ((vb0 ^ (((2 * t + 1) & 3) << 4)) | (((2 * t + 1) & 3) << 8)
                            | (((2 * t + 1) >> 2) << 10)) & vmask;
            f16x8 av0 = *(const f16x8*)(vrbc + o0);
            f16x8 av1 = *(const f16x8*)(vrbc + o1);
            acc = __builtin_amdgcn_mfma_f32_32x32x16_f16(av0, pb0, acc, 0, 0, 0);
            acc = __builtin_amdgcn_mfma_f32_32x32x16_f16(av1, pb1, acc, 0, 0, 0);
        }
        __builtin_amdgcn_s_setprio(0);

        if (c < 7 && tid >= 256) {           // write-late: V regs -> buf^1
#pragma unroll
            for (int jj = 0; jj < 4; jj++) {
                f16x2 pr; pr[0] = va[jj]; pr[1] = vb[jj];
                *(f16x2*)(VA + (cb ^ 1) * 2048 + (vbw3 ^ (jj * 8))) = pr;
            }
        }
    }

    // acc C-layout: col q=n; regs 0-7 -> heads, regs 8-15 -> L (all equal = key-sum).
    float rl = 1.0f / acc[8];
    f16x4 o0, o1;
#pragma unroll
    for (int i = 0; i < 4; i++) o0[i] = (_Float16)(acc[i] * rl);       // heads 4*h5+0..3
#pragma unroll
    for (int i = 0; i < 4; i++) o1[i] = (_Float16)(acc[4 + i] * rl);   // heads 4*h5+8..11
    _Float16* ob = Ah + (size_t)(b * 1024 + q0 + n) * 1024 + g * 16 + h5 * 4;
    *(f16x4*)(ob) = o0;
    *(f16x4*)(ob + 8) = o1;
}

extern "C" void kernel_launch(void* const* d_in, const int* in_sizes, int n_in,
                              void* d_out, int out_size, void* d_ws, size_t ws_size,
                              hipStream_t stream) {
    const float* x1 = (const float*)d_in[0];
    const float* x2 = (const float*)d_in[1];
    const float* Wq = (const float*)d_in[2];
    const float* Wk = (const float*)d_in[3];
    const float* Wv = (const float*)d_in[4];
    const float* Wo = (const float*)d_in[5];

    char* ws = (char*)d_ws;
    const size_t MB = 1u << 20;
    if (ws_size < 56 * MB) return;

    _Float16* x1h = (_Float16*)(ws + 0 * MB);   // 4096x1024
    _Float16* x2h = (_Float16*)(ws + 8 * MB);   // 4096x1024
    _Float16* WqT = (_Float16*)(ws + 16 * MB);  // 1024x1024 (N,K)
    _Float16* WkT = (_Float16*)(ws + 18 * MB);  // contiguous with WvT -> stacked (2048,1024)
    _Float16* WvT = (_Float16*)(ws + 20 * MB);
    _Float16* WoT = (_Float16*)(ws + 22 * MB);
    _Float16* Qh  = (_Float16*)(ws + 24 * MB);  // 4096x1024
    _Float16* Kh  = (_Float16*)(ws + 32 * MB);
    _Float16* Vh  = (_Float16*)(ws + 40 * MB);
    _Float16* Ah  = (_Float16*)(ws + 48 * MB);

    prep_kernel<<<12288, 256, 0, stream>>>(x1, x2, Wq, Wk, Wv, Wo,
                                           x1h, x2h, WqT, WkT, WvT, WoT);

    gemm_qkv_kernel<<<768, 256, 0, stream>>>(x1h, x2h, WqT, WkT, Qh, Kh, Vh);

    attn_kernel<<<1024, 512, 0, stream>>>(Qh, Kh, Vh, Ah);

    gemm_wo_kernel<<<512, 256, 0, stream>>>(Ah, WoT, (float*)d_out);
}

// Round 11
// 177.371 us; speedup vs baseline: 1.2190x; 1.0572x over previous
//
#include <hip/hip_runtime.h>

// B=4, C=C2=1024, E=1024, D=1024, NH(head dim)=16, G=64 groups. Rows B*C=4096.

typedef _Float16 f16x8 __attribute__((ext_vector_type(8)));
typedef _Float16 f16x4 __attribute__((ext_vector_type(4)));
typedef _Float16 f16x2 __attribute__((ext_vector_type(2)));
typedef float    f32x4 __attribute__((ext_vector_type(4)));
typedef float    f32x16 __attribute__((ext_vector_type(16)));

// global -> LDS direct DMA, 16 B per lane. LDS dest = wave-uniform base + lane*16.
#define GLOAD_LDS16(gp, lp)                                              \
    __builtin_amdgcn_global_load_lds(                                    \
        (const __attribute__((address_space(1))) void*)(gp),             \
        (__attribute__((address_space(3))) void*)(lp), 16, 0, 0)

static __device__ __forceinline__ f16x8 pack8f(const float* p) {
    f16x2 a = __builtin_bit_cast(f16x2, __builtin_amdgcn_cvt_pkrtz(p[0], p[1]));
    f16x2 b = __builtin_bit_cast(f16x2, __builtin_amdgcn_cvt_pkrtz(p[2], p[3]));
    f16x2 c = __builtin_bit_cast(f16x2, __builtin_amdgcn_cvt_pkrtz(p[4], p[5]));
    f16x2 d = __builtin_bit_cast(f16x2, __builtin_amdgcn_cvt_pkrtz(p[6], p[7]));
    f16x8 r;
    r[0] = a[0]; r[1] = a[1]; r[2] = b[0]; r[3] = b[1];
    r[4] = c[0]; r[5] = c[1]; r[6] = d[0]; r[7] = d[1];
    return r;
}

// ---- prep: fp32->fp16 convert of x1,x2 (blocks 0..8191) + transpose-convert of the
// ---- 4 weights into (N,K) f16 (blocks 8192..12287), one launch ----
__global__ __launch_bounds__(256) void prep_kernel(
        const float* __restrict__ x1, const float* __restrict__ x2,
        const float* __restrict__ W0, const float* __restrict__ W1,
        const float* __restrict__ W2, const float* __restrict__ W3,
        _Float16* __restrict__ y1, _Float16* __restrict__ y2,
        _Float16* __restrict__ T0, _Float16* __restrict__ T1,
        _Float16* __restrict__ T2, _Float16* __restrict__ T3) {
    int bx = blockIdx.x, tid = threadIdx.x;
    if (bx < 8192) {
        int i = bx * 256 + tid;              // 2M float4 total
        const float* x = (i < 1048576) ? x1 : x2;
        _Float16* y = (i < 1048576) ? y1 : y2;
        int j = i & 1048575;
        float4 v = ((const float4*)x)[j];
        f16x4 h = { (_Float16)v.x, (_Float16)v.y, (_Float16)v.z, (_Float16)v.w };
        ((f16x4*)y)[j] = h;
    } else {
        int z = (bx - 8192) >> 10;
        const float* W = (z == 0) ? W0 : (z == 1) ? W1 : (z == 2) ? W2 : W3;
        _Float16* WT = (z == 0) ? T0 : (z == 1) ? T1 : (z == 2) ? T2 : T3;
        int t = (bx - 8192) & 1023;
        int c0 = (t & 31) * 32, r0 = (t >> 5) * 32;
        __shared__ float tile[32][33];
        int tx = tid & 31, ty = tid >> 5;    // 32 x 8
#pragma unroll
        for (int i = 0; i < 32; i += 8)
            tile[ty + i][tx] = W[(r0 + ty + i) * 1024 + (c0 + tx)];
        __syncthreads();
#pragma unroll
        for (int i = 0; i < 32; i += 8)
            WT[(c0 + ty + i) * 1024 + (r0 + tx)] = (_Float16)tile[tx][ty + i];
    }
}

// ------------- m97-style MTx128 GEMM body (pre-offset pointers, K=1024) -------------
// block 256 (4 waves, 2x2 over MT x 128), BK=64, global_load_lds w16, 16x16x32 MFMA.
// R17 (verified: gemm_qkv 9.4M conflict-cycles -> off top-5, total -7us): T2-style
// LDS XOR-swizzle, both-sides (rule #21). DMA dest linear; global SOURCE column
// pre-swizzled (slot s of row r holds linear column s^(r&7)); reads XOR the same
// involution (row&7 == col&7 at read). Per-lane slot = (ki*4+quad)^(col&7):
// 2-way alias (free). Permutation stays inside each 128B line.
template <int MT, bool OUTF32>
static __device__ __forceinline__ void gemm_body(const _Float16* __restrict__ Atile,
                                                 const _Float16* __restrict__ BTtile,
                                                 void* __restrict__ Ctile,
                                                 _Float16* As, _Float16* Bs) {
    constexpr int AF = MT / 32;              // A staging rounds & m-frags per wave
    const int tid = threadIdx.x, lane = tid & 63, wave = tid >> 6;
    const int wm = wave >> 1, wn = wave & 1;
    const int col = lane & 15, quad = lane >> 4;

    f32x4 acc[AF][4];
#pragma unroll
    for (int i = 0; i < AF; i++)
#pragma unroll
        for (int j = 0; j < 4; j++) acc[i][j] = (f32x4){0.f, 0.f, 0.f, 0.f};

    const int srow = wave * 8 + (lane >> 3);
    // swizzled source column: slot (lane&7) of row (..|lane>>3) holds col slot^(r&7)
    const int sch = ((lane & 7) ^ (lane >> 3)) * 8;
    const _Float16* Ag = Atile + (size_t)srow * 1024 + sch;
    const _Float16* Bg = BTtile + (size_t)srow * 1024 + sch;
    _Float16* Asl = As + wave * 512;
    _Float16* Bsl = Bs + wave * 512;

    const int rsw = (col & 7) * 8;           // read-side XOR (row&7 == col&7)

    for (int kt = 0; kt < 16; kt++) {
        __syncthreads();
#pragma unroll
        for (int c = 0; c < AF; c++)
            GLOAD_LDS16(Ag + (size_t)(c * 32) * 1024 + kt * 64, Asl + c * 2048);
#pragma unroll
        for (int c = 0; c < 4; c++)
            GLOAD_LDS16(Bg + (size_t)(c * 32) * 1024 + kt * 64, Bsl + c * 2048);
        __syncthreads();
#pragma unroll
        for (int ki = 0; ki < 2; ki++) {
            f16x8 af[AF], bf[4];
#pragma unroll
            for (int i = 0; i < AF; i++)
                af[i] = *(const f16x8*)(As + (((wm * (MT / 2) + i * 16 + col) * 64
                                               + ki * 32 + quad * 8) ^ rsw));
#pragma unroll
            for (int j = 0; j < 4; j++)
                bf[j] = *(const f16x8*)(Bs + (((wn * 64 + j * 16 + col) * 64
                                               + ki * 32 + quad * 8) ^ rsw));
#pragma unroll
            for (int i = 0; i < AF; i++)
#pragma unroll
                for (int j = 0; j < 4; j++)
                    acc[i][j] = __builtin_amdgcn_mfma_f32_16x16x32_f16(af[i], bf[j], acc[i][j], 0, 0, 0);
        }
    }

#pragma unroll
    for (int i = 0; i < AF; i++)
#pragma unroll
        for (int ii = 0; ii < 4; ii++) {
            int row = wm * (MT / 2) + i * 16 + quad * 4 + ii;
#pragma unroll
            for (int j = 0; j < 4; j++) {
                int cc = wn * 64 + j * 16 + col;
                if (OUTF32) ((float*)Ctile)[(size_t)row * 1024 + cc] = acc[i][j][ii];
                else ((_Float16*)Ctile)[(size_t)row * 1024 + cc] = (_Float16)acc[i][j][ii];
            }
        }
}

// Fused Q + (KV as N=2048) projections, 768 blocks (128x128 tiles).
// R21: XCD-coherent block swizzle (the R16 attn lever, un-applied here until now).
// Old mapping m=gx>>3: the 8 blocks sharing one 256KB A-tile are consecutive ->
// id%8 lands them on 8 DIFFERENT XCD L2s (attn's pre-R16 pathology; A logical
// re-reads: x1h x8 + x2h x16 = 192MB, FETCH 69MB). New: xcd = gx&7 = f(m-tile),
// all n-blocks of an m-tile share one XCD. Per-XCD set: Q-part 4x256KB A + 2MB W
// = 3MB < 4MB L2; KV-part 1MB A + 4MB W ~ 5MB (A prioritized). Bijective:
// mi = (gx&7) + 8*((gx>>3)&3), ni = gx>>5.
__global__ __launch_bounds__(256, 3) void gemm_qkv_kernel(
        const _Float16* __restrict__ x1h, const _Float16* __restrict__ x2h,
        const _Float16* __restrict__ WqT, const _Float16* __restrict__ WkvT,
        _Float16* __restrict__ Qh, _Float16* __restrict__ Kh, _Float16* __restrict__ Vh) {
    __shared__ _Float16 As[128 * 64], Bs[128 * 64];
    int gx = blockIdx.x;
    const _Float16 *A, *BT;
    _Float16* C;
    int m0, n0;
    if (gx < 256) {
        int x = gx & 7, y = gx >> 3;          // y 0..31
        int mi = x + ((y & 3) << 3);          // 0..31  (XCD = mi&7)
        int ni = y >> 2;                      // 0..7
        m0 = mi * 128; n0 = ni * 128;
        A = x1h; BT = WqT + (size_t)n0 * 1024; C = Qh + n0;
    } else {
        int idx = gx - 256;                   // 0..511 (256%8==0: idx&7 == gx&7)
        int x = idx & 7, y = idx >> 3;        // y 0..63
        int mi = x + ((y & 3) << 3);          // 0..31  (XCD = mi&7)
        int nb = y >> 2;                      // 0..15
        m0 = mi * 128;
        n0 = nb * 128;                        // 0..2047 within stacked KV
        A = x2h; BT = WkvT + (size_t)n0 * 1024;
        C = (nb < 8) ? (Kh + n0) : (Vh + (n0 - 1024));
    }
    gemm_body<128, false>(A + (size_t)m0 * 1024, BT, (void*)(C + (size_t)m0 * 1024), As, Bs);
}

// Wo GEMM: 64x128 tiles -> 512 blocks (2 blocks/CU co-residency).
// R21: XCD swizzle, same rationale: mi = (gx&7) + 8*((gx>>3)&7), ni = gx>>6.
// Per-XCD set: 8 x 128KB A + 2MB W = 3MB < 4MB L2. Bijective.
__global__ __launch_bounds__(256, 4) void gemm_wo_kernel(const _Float16* __restrict__ Ah,
                                                         const _Float16* __restrict__ WoT,
                                                         float* __restrict__ out) {
    __shared__ _Float16 As[64 * 64], Bs[128 * 64];
    int gx = blockIdx.x;
    int x = gx & 7, y = gx >> 3;              // y 0..63
    int mi = x + ((y & 7) << 3);              // 0..63  (XCD = mi&7)
    int ni = y >> 3;                          // 0..7
    int m0 = mi * 64, n0 = ni * 128;
    gemm_body<64, true>(Ah + (size_t)m0 * 1024, WoT + (size_t)n0 * 1024,
                        (void*)(out + (size_t)m0 * 1024 + n0), As, Bs);
}

// ------------- MFMA flash attention (fixed-max softmax), per (b,g) pair -------------
// R16 attn (session-verified optimum of this structure: ~41.5us). K-in-registers
// abandoned (R18/R19): irreducible live state ~72 regs (40 arch + 16 acc + 16
// zero16 in the unified gfx950 VGPR/AGPR file); +8 arch regs spills.
// Structure: XCD-coherent block swizzle (FETCH 74->39 MB verified), double-buffered
// LDS, ONE barrier per chunk, K staged via global_load_lds DMA (pre-permuted global
// addrs, linear LDS dest), V staged by waves 4-7 (swizzled ds_write_b32, 2
// lanes/bank), write-late, setprio around compute.
__global__ __launch_bounds__(512, 6) void attn_kernel(const _Float16* __restrict__ Qh,
                                                      const _Float16* __restrict__ Kh,
                                                      const _Float16* __restrict__ Vh,
                                                      _Float16* __restrict__ Ah) {
    // ---- XCD-coherent swizzle ----
    int L = blockIdx.x;                      // 0..1023
    int xcd = L & 7, y = L >> 3;             // HW: XCD ~= L%8 (round-robin)
    int halfpid = xcd + ((y & 15) << 3);     // 0..127, fixed per XCD
    int pid = (halfpid << 1) | ((y >> 4) & 1);
    int qch = y >> 5;                        // 0..3
    int b = pid >> 6, g = pid & 63;

    __shared__ _Float16 KA[4096];    // 2 bufs x [t:4][lane:64][8 halves]
    __shared__ _Float16 VA[4096];    // 2 bufs x [pvblk:8][kb3][head^swz|hi][klow]
    __shared__ _Float16 ones[8];     // broadcast all-1.0 A-frag for L rows

    const _Float16* Kg = Kh + (size_t)(b * 1024) * 1024 + g * 16;
    const _Float16* Vg = Vh + (size_t)(b * 1024) * 1024 + g * 16;
    int tid = threadIdx.x;
    if (tid < 8) ones[tid] = (_Float16)1.f;

    int lane = tid & 63, wave = tid >> 6;    // wave 0..7
    int n = lane & 31, h5 = lane >> 5;       // n = q (S/PV col), also PV A-row m
    int q0 = qch * 256 + wave * 32;

    // Q B-frag: B[k=head=h5*8+j][n=q]; fold 0.25*log2(e) -> scores in log2 domain.
    f16x8 qf;
    {
        f16x8 t = *(const f16x8*)(Qh + (size_t)(b * 1024 + q0 + n) * 1024 + g * 16 + h5 * 8);
#pragma unroll
        for (int j = 0; j < 8; j++) qf[j] = (_Float16)((float)t[j] * 0.360673760f);
    }

    f32x16 acc = {0.f, 0.f, 0.f, 0.f, 0.f, 0.f, 0.f, 0.f,
                  0.f, 0.f, 0.f, 0.f, 0.f, 0.f, 0.f, 0.f};
    const f32x16 zero16 = acc;

    // ---- K DMA source (waves 0-3): per-lane pre-permuted global addr ----
    const int pl = lane & 31;
    const int kperm = (pl & 19) | ((pl & 4) << 1) | ((pl & 8) >> 1);   // swap bits 2,3
    const _Float16* ksrc = Kg + (size_t)((wave & 3) * 32 + kperm) * 1024 + (lane >> 5) * 8;
    _Float16* kdst = KA + (wave & 3) * 512;          // + bufsel*2048

    // ---- V staging (waves 4-7): u in [0,256), pair (vk0,vk0+1), 4 heads ----
    const int u = tid & 255;
    const int vk0 = (u & 63) * 2;
    const int hq = u >> 6;                   // head quad 0..3
    const int vpart = hq >> 1, jb = (hq & 1) * 4;
    const _Float16* vsrcA = Vg + (size_t)vk0 * 1024 + vpart * 8 + jb;
    const int vbw3 = ((((vk0 >> 4) * 256) + ((vk0 >> 3) & 1) * 128 + vpart * 64 + (vk0 & 7))
                      ^ (((vk0 >> 3) & 7) << 3)) ^ (jb * 8);

    // ---- compute-side V read: single base reg + folded per-pvblk immediates ----
    // addr(s) = ((vb0 ^ ((s&3)<<4)) | ((s&3)<<8) | ((s>>2)<<10)) & vmask
    const int vb0 = h5 * 128 + ((n & 8) | ((n & 7) ^ h5)) * 8;
    const int vmask = (n < 16) ? -1 : 0;     // ones-lanes: offset 0 -> broadcast
    const _Float16* vrb = (n < 16) ? VA : ones;
    const int vbufstep = (n < 16) ? 2048 : 0;

    // ---- prologue: stage chunk 0 into buf 0 ----
    if (tid < 256) {
        GLOAD_LDS16(ksrc, kdst);
    } else {
        f16x4 va = *(const f16x4*)(vsrcA);
        f16x4 vb = *(const f16x4*)(vsrcA + 1024);
#pragma unroll
        for (int jj = 0; jj < 4; jj++) {
            f16x2 pr; pr[0] = va[jj]; pr[1] = vb[jj];
            *(f16x2*)(VA + (vbw3 ^ (jj * 8))) = pr;
        }
    }

    for (int c = 0; c < 8; c++) {            // 128-key chunks
        __syncthreads();                     // buf[c&1] staged; buf[c&1^1] free
        const int cb = c & 1;
        f16x4 va, vb;
        if (c < 7) {                         // issue next chunk's staging early
            if (tid < 256) {
                GLOAD_LDS16(ksrc + (size_t)((c + 1) * 128) * 1024, kdst + (cb ^ 1) * 2048);
            } else {
                va = *(const f16x4*)(vsrcA + (size_t)((c + 1) * 128) * 1024);
                vb = *(const f16x4*)(vsrcA + (size_t)((c + 1) * 128) * 1024 + 1024);
            }
        }
        const _Float16* akc = KA + cb * 2048;
        const _Float16* vrbc = vrb + cb * vbufstep;

        __builtin_amdgcn_s_setprio(1);
#pragma unroll
        for (int t = 0; t < 4; t++) {        // 32 keys per iteration
            f16x8 ak = *(const f16x8*)(akc + (t * 64 + lane) * 8);
            f32x16 s = __builtin_amdgcn_mfma_f32_32x32x16_f16(ak, qf, zero16, 0, 0, 0);
            float p[16];
#pragma unroll
            for (int i = 0; i < 16; i++) p[i] = __builtin_amdgcn_exp2f(s[i]);
            f16x8 pb0 = pack8f(p);           // keys t*32 + 0..15  (k=h5*8+j)
            f16x8 pb1 = pack8f(p + 8);       // keys t*32 + 16..31
            const int o0 = ((vb0 ^ (((2 * t) & 3) << 4)) | (((2 * t) & 3) << 8)
                            | (((2 * t) >> 2) << 10)) & vmask;
            const int o1 = ((vb0 ^ (((2 * t + 1) & 3) << 4)) | (((2 * t + 1) & 3) << 8)
                            | (((2 * t + 1) >> 2) << 10)) & vmask;
            f16x8 av0 = *(const f16x8*)(vrbc + o0);
            f16x8 av1 = *(const f16x8*)(vrbc + o1);
            acc = __builtin_amdgcn_mfma_f32_32x32x16_f16(av0, pb0, acc, 0, 0, 0);
            acc = __builtin_amdgcn_mfma_f32_32x32x16_f16(av1, pb1, acc, 0, 0, 0);
        }
        __builtin_amdgcn_s_setprio(0);

        if (c < 7 && tid >= 256) {           // write-late: V regs -> buf^1
#pragma unroll
            for (int jj = 0; jj < 4; jj++) {
                f16x2 pr; pr[0] = va[jj]; pr[1] = vb[jj];
                *(f16x2*)(VA + (cb ^ 1) * 2048 + (vbw3 ^ (jj * 8))) = pr;
            }
        }
    }

    // acc C-layout: col q=n; regs 0-7 -> heads, regs 8-15 -> L (all equal = key-sum).
    float rl = 1.0f / acc[8];
    f16x4 o0, o1;
#pragma unroll
    for (int i = 0; i < 4; i++) o0[i] = (_Float16)(acc[i] * rl);       // heads 4*h5+0..3
#pragma unroll
    for (int i = 0; i < 4; i++) o1[i] = (_Float16)(acc[4 + i] * rl);   // heads 4*h5+8..11
    _Float16* ob = Ah + (size_t)(b * 1024 + q0 + n) * 1024 + g * 16 + h5 * 4;
    *(f16x4*)(ob) = o0;
    *(f16x4*)(ob + 8) = o1;
}

extern "C" void kernel_launch(void* const* d_in, const int* in_sizes, int n_in,
                              void* d_out, int out_size, void* d_ws, size_t ws_size,
                              hipStream_t stream) {
    const float* x1 = (const float*)d_in[0];
    const float* x2 = (const float*)d_in[1];
    const float* Wq = (const float*)d_in[2];
    const float* Wk = (const float*)d_in[3];
    const float* Wv = (const float*)d_in[4];
    const float* Wo = (const float*)d_in[5];

    char* ws = (char*)d_ws;
    const size_t MB = 1u << 20;
    if (ws_size < 56 * MB) return;

    _Float16* x1h = (_Float16*)(ws + 0 * MB);   // 4096x1024
    _Float16* x2h = (_Float16*)(ws + 8 * MB);   // 4096x1024
    _Float16* WqT = (_Float16*)(ws + 16 * MB);  // 1024x1024 (N,K)
    _Float16* WkT = (_Float16*)(ws + 18 * MB);  // contiguous with WvT -> stacked (2048,1024)
    _Float16* WvT = (_Float16*)(ws + 20 * MB);
    _Float16* WoT = (_Float16*)(ws + 22 * MB);
    _Float16* Qh  = (_Float16*)(ws + 24 * MB);  // 4096x1024
    _Float16* Kh  = (_Float16*)(ws + 32 * MB);
    _Float16* Vh  = (_Float16*)(ws + 40 * MB);
    _Float16* Ah  = (_Float16*)(ws + 48 * MB);

    prep_kernel<<<12288, 256, 0, stream>>>(x1, x2, Wq, Wk, Wv, Wo,
                                           x1h, x2h, WqT, WkT, WvT, WoT);

    gemm_qkv_kernel<<<768, 256, 0, stream>>>(x1h, x2h, WqT, WkT, Qh, Kh, Vh);

    attn_kernel<<<1024, 512, 0, stream>>>(Qh, Kh, Vh, Ah);

    gemm_wo_kernel<<<512, 256, 0, stream>>>(Ah, WoT, (float*)d_out);
}